// Round 6
// baseline (219.153 us; speedup 1.0000x reference)
//
#include <hip/hip_runtime.h>
#include <hip/hip_bf16.h>

#define S_LEN 8192
#define D_MODEL 512
#define NH 8
#define HD 64
#define WIN 256
#define NB 2

typedef __hip_bfloat16 bf16;
typedef __attribute__((ext_vector_type(8))) short short8;
typedef __attribute__((ext_vector_type(4))) float f32x4;

static __device__ __forceinline__ short f2bf(float f) {
    bf16 h = __float2bfloat16(f);
    return *reinterpret_cast<short*>(&h);
}

static __device__ __forceinline__ void gload_lds16(short* lds, const short* g) {
    __builtin_amdgcn_global_load_lds(
        (const __attribute__((address_space(1))) void*)g,
        (__attribute__((address_space(3))) void*)lds, 16, 0, 0);
}

// ---------------------------------------------------------------------------
// x (fp32 [16384][512]) -> xb (bf16), flat convert
// ---------------------------------------------------------------------------
__global__ __launch_bounds__(256) void convert_x_kernel(
    const float* __restrict__ x, short* __restrict__ xb)
{
    const int n4 = (NB * S_LEN * D_MODEL) / 4;
    for (int i = blockIdx.x * 256 + threadIdx.x; i < n4; i += gridDim.x * 256) {
        float4 v = ((const float4*)x)[i];
        short4 o;
        o.x = f2bf(v.x); o.y = f2bf(v.y); o.z = f2bf(v.z); o.w = f2bf(v.w);
        ((short4*)xb)[i] = o;
    }
}

// ---------------------------------------------------------------------------
// W (fp32 [k][n]) -> wT (bf16 [n][k]) for the 3 weights (blockIdx.z)
// ---------------------------------------------------------------------------
__global__ __launch_bounds__(256) void convert_wT_kernel(
    const float* __restrict__ Wq, const float* __restrict__ Wk,
    const float* __restrict__ Wv, short* __restrict__ wT)
{
    __shared__ float t[32][33];
    const float* W = blockIdx.z == 0 ? Wq : (blockIdx.z == 1 ? Wk : Wv);
    const int n0 = blockIdx.x * 32, k0 = blockIdx.y * 32;
    const int tx = threadIdx.x & 31, ty = threadIdx.x >> 5;
#pragma unroll
    for (int i = 0; i < 4; ++i)
        t[ty + 8 * i][tx] = W[(size_t)(k0 + ty + 8 * i) * D_MODEL + n0 + tx];
    __syncthreads();
#pragma unroll
    for (int i = 0; i < 4; ++i) {
        const int nl = ty + 8 * i, kl = tx;
        wT[(size_t)blockIdx.z * D_MODEL * D_MODEL +
           (size_t)(n0 + nl) * D_MODEL + k0 + kl] = f2bf(t[kl][nl]);
    }
}

// ---------------------------------------------------------------------------
// bf16 MFMA projection GEMM: C = xb @ wT^T (+bias)*scale.
// q,k stored head-major [bh][s][d]; v stored TRANSPOSED [bh][d][s].
// ---------------------------------------------------------------------------
__global__ __launch_bounds__(256) void proj_mfma_kernel(
    const short* __restrict__ xb, const short* __restrict__ wT,
    const float* __restrict__ bq, const float* __restrict__ bk,
    const float* __restrict__ bv, bf16* __restrict__ qkv)
{
    __shared__ short Ash[128 * 64];
    __shared__ short Bsh[128 * 64];

    const int widx = blockIdx.x >> 2;
    const int col0 = (blockIdx.x & 3) * 128;
    const int row0 = blockIdx.y * 128;
    const int tid  = threadIdx.x;
    const int w    = tid >> 6;
    const int lane = tid & 63;
    const int col  = lane & 15;
    const int kg   = lane >> 4;

    const float* bias = widx == 0 ? bq : (widx == 1 ? bk : bv);
    const float scale = widx == 0 ? 0.125f : 1.0f;
    const short* wbase = wT + (size_t)widx * D_MODEL * D_MODEL;

    const f32x4 zero4 = {0.f, 0.f, 0.f, 0.f};
    f32x4 acc[4][4];
#pragma unroll
    for (int i = 0; i < 4; ++i)
#pragma unroll
        for (int j = 0; j < 4; ++j) acc[i][j] = zero4;

    const int wm0 = (w >> 1) * 64;
    const int wn0 = (w & 1) * 64;

    for (int kb = 0; kb < D_MODEL; kb += 64) {
#pragma unroll
        for (int ci = 0; ci < 4; ++ci) {
            const int Lb = w * 256 + ci * 64;
            const int L  = Lb + lane;
            const int m  = L >> 3;
            const int kc = ((L & 7) - (m >> 1)) & 7;
            const int ko = kb + kc * 8;
            gload_lds16(Ash + (size_t)Lb * 8,
                        xb + (size_t)(row0 + m) * D_MODEL + ko);
            gload_lds16(Bsh + (size_t)Lb * 8,
                        wbase + (size_t)(col0 + m) * D_MODEL + ko);
        }
        __syncthreads();

#pragma unroll
        for (int s = 0; s < 2; ++s) {
            short8 af[4], bfr[4];
#pragma unroll
            for (int mt = 0; mt < 4; ++mt) {
                const int m = wm0 + mt * 16 + col;
                const int c = m * 8 + ((s * 4 + kg + (m >> 1)) & 7);
                af[mt] = *(const short8*)(Ash + (size_t)c * 8);
            }
#pragma unroll
            for (int nt = 0; nt < 4; ++nt) {
                const int n = wn0 + nt * 16 + col;
                const int c = n * 8 + ((s * 4 + kg + (n >> 1)) & 7);
                bfr[nt] = *(const short8*)(Bsh + (size_t)c * 8);
            }
#pragma unroll
            for (int mt = 0; mt < 4; ++mt)
#pragma unroll
                for (int nt = 0; nt < 4; ++nt)
                    acc[mt][nt] = __builtin_amdgcn_mfma_f32_16x16x32_bf16(
                        af[mt], bfr[nt], acc[mt][nt], 0, 0, 0);
        }
        __syncthreads();
    }

    bf16* dst = qkv + (size_t)widx * (NB * NH * S_LEN * HD);
#pragma unroll
    for (int nt = 0; nt < 4; ++nt) {
        const int n = col0 + wn0 + nt * 16 + col;
        const float bias_v = bias[n];
        const int h = n >> 6, d = n & 63;
#pragma unroll
        for (int mt = 0; mt < 4; ++mt) {
            const int m0 = row0 + wm0 + mt * 16 + kg * 4;
            const int b = m0 >> 13, s0 = m0 & (S_LEN - 1);
            if (widx == 2) {
                short4 pk;
                pk.x = f2bf(acc[mt][nt][0] + bias_v);
                pk.y = f2bf(acc[mt][nt][1] + bias_v);
                pk.z = f2bf(acc[mt][nt][2] + bias_v);
                pk.w = f2bf(acc[mt][nt][3] + bias_v);
                *(short4*)&dst[(((size_t)(b * NH + h)) * HD + d) * S_LEN + s0] = pk;
            } else {
#pragma unroll
                for (int r = 0; r < 4; ++r)
                    dst[(((size_t)(b * NH + h)) * S_LEN + s0 + r) * HD + d] =
                        __float2bfloat16((acc[mt][nt][r] + bias_v) * scale);
            }
        }
    }
}

// ---------------------------------------------------------------------------
// Fallback fp32 projection (only if ws too small)
// ---------------------------------------------------------------------------
__global__ __launch_bounds__(256) void proj_kernel(
    const float* __restrict__ x, const float* __restrict__ Wm,
    const float* __restrict__ bias, bf16* __restrict__ dst, float scale,
    int transpose_v)
{
    __shared__ float As[16][64];
    __shared__ float Bs[16][64];
    const int tid  = threadIdx.x;
    const int row0 = blockIdx.y * 64;
    const int col0 = blockIdx.x * 64;
    const int ty = tid >> 4, tx = tid & 15;
    const int t4 = tid * 4;
    const int ai = t4 >> 4, aj = t4 & 15;
    const int bj = t4 >> 6, bi = t4 & 63;
    float acc[4][4] = {};
    for (int kb = 0; kb < D_MODEL; kb += 16) {
        float4 av = *(const float4*)(x  + (size_t)(row0 + ai) * D_MODEL + kb + aj);
        float4 bv = *(const float4*)(Wm + (size_t)(kb + bj)  * D_MODEL + col0 + bi);
        As[aj + 0][ai] = av.x; As[aj + 1][ai] = av.y;
        As[aj + 2][ai] = av.z; As[aj + 3][ai] = av.w;
        *(float4*)(&Bs[bj][bi]) = bv;
        __syncthreads();
#pragma unroll
        for (int k = 0; k < 16; ++k) {
            float a[4], b[4];
#pragma unroll
            for (int ii = 0; ii < 4; ++ii) a[ii] = As[k][ty * 4 + ii];
#pragma unroll
            for (int jj = 0; jj < 4; ++jj) b[jj] = Bs[k][tx * 4 + jj];
#pragma unroll
            for (int ii = 0; ii < 4; ++ii)
#pragma unroll
                for (int jj = 0; jj < 4; ++jj) acc[ii][jj] += a[ii] * b[jj];
        }
        __syncthreads();
    }
#pragma unroll
    for (int ii = 0; ii < 4; ++ii) {
        const int m = row0 + ty * 4 + ii;
        const int b = m >> 13, s = m & (S_LEN - 1);
#pragma unroll
        for (int jj = 0; jj < 4; ++jj) {
            const int n = col0 + tx * 4 + jj;
            const int h = n >> 6, d = n & 63;
            const float v = (acc[ii][jj] + bias[n]) * scale;
            if (transpose_v)
                dst[(((size_t)(b * NH + h)) * HD + d) * S_LEN + s] = __float2bfloat16(v);
            else
                dst[(((size_t)(b * NH + h)) * S_LEN + s) * HD + d] = __float2bfloat16(v);
        }
    }
}

// ---------------------------------------------------------------------------
// Flash sliding-window attention v4:
//   K: double-buffered async LDS staging (global_load_lds 16B, XOR swizzle).
//   V: registers, direct from pre-transposed global vt[bh][d][s]. Fragments
//      issued at the TOP of each tile iteration (before the K-DMA issue, so
//      the compiler can wait on them with vmcnt(2) without draining the DMA)
//      and consumed only after QK^T+softmax (~400 cyc prefetch distance).
//   LDS = 25.6 KB (was 41.9 KB) -> 4 blocks/CU; VGPR ~110 -> 4 waves/SIMD.
//   Grid: x = q-tile, y = bh so consecutive blocks share K/V in XCD L2.
// ---------------------------------------------------------------------------
__global__ __launch_bounds__(256) void attn_mfma4_kernel(
    const bf16* __restrict__ qw, const bf16* __restrict__ kw,
    const bf16* __restrict__ vt, float* __restrict__ out)
{
    __shared__ __align__(16) short Ksh[2][4096];     // [key][d] swizzled, 2x8KB
    __shared__ __align__(16) short Psh[4][16][72];   // per-wave [q][key]

    const int bh   = blockIdx.y;
    const int qt0  = blockIdx.x * 64;
    const int tid  = threadIdx.x;
    const int w    = tid >> 6;
    const int lane = tid & 63;
    const int col  = lane & 15;
    const int kg   = lane >> 4;
    const int q0   = qt0 + w * 16;
    const int q    = q0 + col;
    const size_t base = (size_t)bh * S_LEN * HD;

    const short* qg  = (const short*)qw;
    const short* kgp = (const short*)kw;
    const short* vgp = (const short*)vt;

    const int kt_lo = qt0 - WIN < 0 ? 0 : qt0 - WIN;
    const int kt_hi = qt0 + WIN > S_LEN - 64 ? S_LEN - 64 : qt0 + WIN;
    const int NT    = ((kt_hi - kt_lo) >> 6) + 1;

    // K staging: 512 16B-chunks per tile, 2 per thread, XOR swizzle
    const int p0 = tid, p1 = tid + 256;
    const int r0 = p0 >> 3, c0 = (p0 & 7) ^ (r0 & 7);
    const int r1 = p1 >> 3, c1 = (p1 & 7) ^ (r1 & 7);
    const int ldsb0 = w * 64 * 8;          // wave-uniform chunk base (shorts)
    const int ldsb1 = (w * 64 + 256) * 8;

    // Q B-frag: B[n=q][k=d]
    const short* qptr = qg + base + (size_t)q * HD + kg * 8;
    const short8 qB0 = *(const short8*)(qptr);
    const short8 qB1 = *(const short8*)(qptr + 32);

    const f32x4 zero4 = {0.f, 0.f, 0.f, 0.f};
    f32x4 Oacc[4] = {zero4, zero4, zero4, zero4};
    float m = -1e30f, l = 0.f;

    const int x7 = col & 7;

    // prologue: stage K tile 0 into buffer 0
    gload_lds16(&Ksh[0][ldsb0], kgp + base + (size_t)(kt_lo + r0) * HD + c0 * 8);
    gload_lds16(&Ksh[0][ldsb1], kgp + base + (size_t)(kt_lo + r1) * HD + c1 * 8);

    for (int i = 0; i < NT; ++i) {
        __syncthreads();   // drains K DMA for tile i (issued last iteration)

        const int kt = kt_lo + 64 * i;

        // ---- V fragments for THIS tile: issue now, consume after softmax ----
        short8 vA0[4], vA1[4];
#pragma unroll
        for (int dt = 0; dt < 4; ++dt) {
            const short* vp = vgp + base + (size_t)(dt * 16 + col) * S_LEN + kt + kg * 8;
            vA0[dt] = *(const short8*)(vp);
            vA1[dt] = *(const short8*)(vp + 32);
        }

        if (i + 1 < NT) {  // K DMA for tile i+1 (issued AFTER the V loads)
            const int ktn = kt_lo + 64 * (i + 1);
            const int nb = (i + 1) & 1;
            gload_lds16(&Ksh[nb][ldsb0], kgp + base + (size_t)(ktn + r0) * HD + c0 * 8);
            gload_lds16(&Ksh[nb][ldsb1], kgp + base + (size_t)(ktn + r1) * HD + c1 * 8);
        }

        const short* Kb = Ksh[i & 1];

        // ---- S^T = K . Q^T : A[m=key][k=d] from swizzled LDS ----
        f32x4 sc[4];
#pragma unroll
        for (int t = 0; t < 4; ++t) {
            const int key = 16 * t + col;
            const short8 kA0 = *(const short8*)(Kb + (size_t)(key * 8 + (kg ^ x7)) * 8);
            const short8 kA1 = *(const short8*)(Kb + (size_t)(key * 8 + ((kg + 4) ^ x7)) * 8);
            f32x4 a = zero4;
            a = __builtin_amdgcn_mfma_f32_16x16x32_bf16(kA0, qB0, a, 0, 0, 0);
            a = __builtin_amdgcn_mfma_f32_16x16x32_bf16(kA1, qB1, a, 0, 0, 0);
            sc[t] = a;                     // sc[t][r] = S[kt+16t+4kg+r][q]
        }

        const bool need_mask = (kt == qt0 - WIN) || (kt == qt0 + WIN);
        if (need_mask) {
#pragma unroll
            for (int t = 0; t < 4; ++t)
#pragma unroll
                for (int r = 0; r < 4; ++r) {
                    const int j = kt + 16 * t + kg * 4 + r;
                    if (j < q - WIN || j > q + WIN) sc[t][r] = -1e30f;
                }
        }

        // ---- per-lane online softmax + cross-kg reduce ----
        float tmax = -1e30f;
#pragma unroll
        for (int t = 0; t < 4; ++t)
#pragma unroll
            for (int r = 0; r < 4; ++r) tmax = fmaxf(tmax, sc[t][r]);
        tmax = fmaxf(tmax, __shfl_xor(tmax, 16));
        tmax = fmaxf(tmax, __shfl_xor(tmax, 32));
        const float mnew = fmaxf(m, tmax);
        const float alpha = __expf(m - mnew);
        m = mnew;

        float p[4][4];
        float rs = 0.f;
        if (need_mask) {
#pragma unroll
            for (int t = 0; t < 4; ++t)
#pragma unroll
                for (int r = 0; r < 4; ++r) {
                    const float pv = (sc[t][r] > -1e29f) ? __expf(sc[t][r] - mnew) : 0.f;
                    p[t][r] = pv; rs += pv;
                }
        } else {
#pragma unroll
            for (int t = 0; t < 4; ++t)
#pragma unroll
                for (int r = 0; r < 4; ++r) {
                    const float pv = __expf(sc[t][r] - mnew);
                    p[t][r] = pv; rs += pv;
                }
        }
        rs += __shfl_xor(rs, 16);
        rs += __shfl_xor(rs, 32);
        l = l * alpha + rs;

        // ---- P -> per-wave LDS (4x b64), read back as B-frags ----
#pragma unroll
        for (int t = 0; t < 4; ++t) {
            short4 pk;
            pk.x = f2bf(p[t][0]); pk.y = f2bf(p[t][1]);
            pk.z = f2bf(p[t][2]); pk.w = f2bf(p[t][3]);
            *(short4*)&Psh[w][col][16 * t + 4 * kg] = pk;
        }

#pragma unroll
        for (int dt = 0; dt < 4; ++dt)
#pragma unroll
            for (int r = 0; r < 4; ++r) Oacc[dt][r] *= alpha;

        const short* pp = &Psh[w][col][kg * 8];   // same-wave RAW: in-order DS
        const short8 pB0 = *(const short8*)(pp);
        const short8 pB1 = *(const short8*)(pp + 32);

        // ---- O^T += V^T . P^T : V fragments from registers ----
#pragma unroll
        for (int dt = 0; dt < 4; ++dt) {
            Oacc[dt] = __builtin_amdgcn_mfma_f32_16x16x32_bf16(vA0[dt], pB0, Oacc[dt], 0, 0, 0);
            Oacc[dt] = __builtin_amdgcn_mfma_f32_16x16x32_bf16(vA1[dt], pB1, Oacc[dt], 0, 0, 0);
        }
    }

    // ---- epilogue: coalesced float4 stores ----
    const float inv = 1.0f / l;
    const int b = bh >> 3, h = bh & 7;
    float* op = out + ((size_t)(b * S_LEN + q)) * D_MODEL + h * HD + kg * 4;
#pragma unroll
    for (int dt = 0; dt < 4; ++dt) {
        float4 o;
        o.x = Oacc[dt][0] * inv; o.y = Oacc[dt][1] * inv;
        o.z = Oacc[dt][2] * inv; o.w = Oacc[dt][3] * inv;
        *(float4*)(op + dt * 16) = o;
    }
}

// ---------------------------------------------------------------------------
extern "C" void kernel_launch(void* const* d_in, const int* in_sizes, int n_in,
                              void* d_out, int out_size, void* d_ws, size_t ws_size,
                              hipStream_t stream)
{
    const float* x  = (const float*)d_in[0];
    const float* Wq = (const float*)d_in[1];
    const float* bq = (const float*)d_in[2];
    const float* Wk = (const float*)d_in[3];
    const float* bk = (const float*)d_in[4];
    const float* Wv = (const float*)d_in[5];
    const float* bv = (const float*)d_in[6];
    float* out = (float*)d_out;

    const size_t n_elem = (size_t)NB * NH * S_LEN * HD;
    bf16* qw = (bf16*)d_ws;
    bf16* kw = qw + n_elem;
    bf16* vw = kw + n_elem;        // v TRANSPOSED: [bh][d][s]
    short* xb = (short*)(vw + n_elem);
    short* wT = xb + (size_t)NB * S_LEN * D_MODEL;

    const size_t need = (3 * n_elem + (size_t)NB * S_LEN * D_MODEL +
                         3 * (size_t)D_MODEL * D_MODEL) * sizeof(short);

    if (ws_size >= need) {
        convert_x_kernel<<<2048, 256, 0, stream>>>(x, xb);
        dim3 wgrid(D_MODEL / 32, D_MODEL / 32, 3);
        convert_wT_kernel<<<wgrid, 256, 0, stream>>>(Wq, Wk, Wv, wT);
        dim3 ggrid(12, (NB * S_LEN) / 128);
        proj_mfma_kernel<<<ggrid, 256, 0, stream>>>(xb, wT, bq, bk, bv, qw);
    } else {
        dim3 pgrid(D_MODEL / 64, (NB * S_LEN) / 64);
        proj_kernel<<<pgrid, 256, 0, stream>>>(x, Wq, bq, qw, 0.125f, 0);
        proj_kernel<<<pgrid, 256, 0, stream>>>(x, Wk, bk, kw, 1.0f, 0);
        proj_kernel<<<pgrid, 256, 0, stream>>>(x, Wv, bv, vw, 1.0f, 1);
    }

    dim3 agrid(S_LEN / 64, NB * NH);
    attn_mfma4_kernel<<<agrid, 256, 0, stream>>>(qw, kw, vw, out);
}

// Round 7
// 180.604 us; speedup vs baseline: 1.2134x; 1.2134x over previous
//
#include <hip/hip_runtime.h>
#include <hip/hip_bf16.h>

#define S_LEN 8192
#define D_MODEL 512
#define NH 8
#define HD 64
#define WIN 256
#define NB 2

typedef __hip_bfloat16 bf16;
typedef __attribute__((ext_vector_type(8))) short short8;
typedef __attribute__((ext_vector_type(4))) float f32x4;

static __device__ __forceinline__ short f2bf(float f) {
    bf16 h = __float2bfloat16(f);
    return *reinterpret_cast<short*>(&h);
}

static __device__ __forceinline__ void gload_lds16(short* lds, const short* g) {
    __builtin_amdgcn_global_load_lds(
        (const __attribute__((address_space(1))) void*)g,
        (__attribute__((address_space(3))) void*)lds, 16, 0, 0);
}

// ---------------------------------------------------------------------------
// x (fp32 [16384][512]) -> xb (bf16), flat convert
// ---------------------------------------------------------------------------
__global__ __launch_bounds__(256) void convert_x_kernel(
    const float* __restrict__ x, short* __restrict__ xb)
{
    const int n4 = (NB * S_LEN * D_MODEL) / 4;
    for (int i = blockIdx.x * 256 + threadIdx.x; i < n4; i += gridDim.x * 256) {
        float4 v = ((const float4*)x)[i];
        short4 o;
        o.x = f2bf(v.x); o.y = f2bf(v.y); o.z = f2bf(v.z); o.w = f2bf(v.w);
        ((short4*)xb)[i] = o;
    }
}

// ---------------------------------------------------------------------------
// W (fp32 [k][n]) -> wT (bf16 [n][k]) for the 3 weights (blockIdx.z)
// ---------------------------------------------------------------------------
__global__ __launch_bounds__(256) void convert_wT_kernel(
    const float* __restrict__ Wq, const float* __restrict__ Wk,
    const float* __restrict__ Wv, short* __restrict__ wT)
{
    __shared__ float t[32][33];
    const float* W = blockIdx.z == 0 ? Wq : (blockIdx.z == 1 ? Wk : Wv);
    const int n0 = blockIdx.x * 32, k0 = blockIdx.y * 32;
    const int tx = threadIdx.x & 31, ty = threadIdx.x >> 5;
#pragma unroll
    for (int i = 0; i < 4; ++i)
        t[ty + 8 * i][tx] = W[(size_t)(k0 + ty + 8 * i) * D_MODEL + n0 + tx];
    __syncthreads();
#pragma unroll
    for (int i = 0; i < 4; ++i) {
        const int nl = ty + 8 * i, kl = tx;
        wT[(size_t)blockIdx.z * D_MODEL * D_MODEL +
           (size_t)(n0 + nl) * D_MODEL + k0 + kl] = f2bf(t[kl][nl]);
    }
}

// ---------------------------------------------------------------------------
// bf16 MFMA projection GEMM: C = xb @ wT^T (+bias)*scale.
// q,k stored head-major [bh][s][d]; v stored TRANSPOSED [bh][d][s].
// ---------------------------------------------------------------------------
__global__ __launch_bounds__(256) void proj_mfma_kernel(
    const short* __restrict__ xb, const short* __restrict__ wT,
    const float* __restrict__ bq, const float* __restrict__ bk,
    const float* __restrict__ bv, bf16* __restrict__ qkv)
{
    __shared__ short Ash[128 * 64];
    __shared__ short Bsh[128 * 64];

    const int widx = blockIdx.x >> 2;
    const int col0 = (blockIdx.x & 3) * 128;
    const int row0 = blockIdx.y * 128;
    const int tid  = threadIdx.x;
    const int w    = tid >> 6;
    const int lane = tid & 63;
    const int col  = lane & 15;
    const int kg   = lane >> 4;

    const float* bias = widx == 0 ? bq : (widx == 1 ? bk : bv);
    const float scale = widx == 0 ? 0.125f : 1.0f;
    const short* wbase = wT + (size_t)widx * D_MODEL * D_MODEL;

    const f32x4 zero4 = {0.f, 0.f, 0.f, 0.f};
    f32x4 acc[4][4];
#pragma unroll
    for (int i = 0; i < 4; ++i)
#pragma unroll
        for (int j = 0; j < 4; ++j) acc[i][j] = zero4;

    const int wm0 = (w >> 1) * 64;
    const int wn0 = (w & 1) * 64;

    for (int kb = 0; kb < D_MODEL; kb += 64) {
#pragma unroll
        for (int ci = 0; ci < 4; ++ci) {
            const int Lb = w * 256 + ci * 64;
            const int L  = Lb + lane;
            const int m  = L >> 3;
            const int kc = ((L & 7) - (m >> 1)) & 7;
            const int ko = kb + kc * 8;
            gload_lds16(Ash + (size_t)Lb * 8,
                        xb + (size_t)(row0 + m) * D_MODEL + ko);
            gload_lds16(Bsh + (size_t)Lb * 8,
                        wbase + (size_t)(col0 + m) * D_MODEL + ko);
        }
        __syncthreads();

#pragma unroll
        for (int s = 0; s < 2; ++s) {
            short8 af[4], bfr[4];
#pragma unroll
            for (int mt = 0; mt < 4; ++mt) {
                const int m = wm0 + mt * 16 + col;
                const int c = m * 8 + ((s * 4 + kg + (m >> 1)) & 7);
                af[mt] = *(const short8*)(Ash + (size_t)c * 8);
            }
#pragma unroll
            for (int nt = 0; nt < 4; ++nt) {
                const int n = wn0 + nt * 16 + col;
                const int c = n * 8 + ((s * 4 + kg + (n >> 1)) & 7);
                bfr[nt] = *(const short8*)(Bsh + (size_t)c * 8);
            }
#pragma unroll
            for (int mt = 0; mt < 4; ++mt)
#pragma unroll
                for (int nt = 0; nt < 4; ++nt)
                    acc[mt][nt] = __builtin_amdgcn_mfma_f32_16x16x32_bf16(
                        af[mt], bfr[nt], acc[mt][nt], 0, 0, 0);
        }
        __syncthreads();
    }

    bf16* dst = qkv + (size_t)widx * (NB * NH * S_LEN * HD);
#pragma unroll
    for (int nt = 0; nt < 4; ++nt) {
        const int n = col0 + wn0 + nt * 16 + col;
        const float bias_v = bias[n];
        const int h = n >> 6, d = n & 63;
#pragma unroll
        for (int mt = 0; mt < 4; ++mt) {
            const int m0 = row0 + wm0 + mt * 16 + kg * 4;
            const int b = m0 >> 13, s0 = m0 & (S_LEN - 1);
            if (widx == 2) {
                short4 pk;
                pk.x = f2bf(acc[mt][nt][0] + bias_v);
                pk.y = f2bf(acc[mt][nt][1] + bias_v);
                pk.z = f2bf(acc[mt][nt][2] + bias_v);
                pk.w = f2bf(acc[mt][nt][3] + bias_v);
                *(short4*)&dst[(((size_t)(b * NH + h)) * HD + d) * S_LEN + s0] = pk;
            } else {
#pragma unroll
                for (int r = 0; r < 4; ++r)
                    dst[(((size_t)(b * NH + h)) * S_LEN + s0 + r) * HD + d] =
                        __float2bfloat16((acc[mt][nt][r] + bias_v) * scale);
            }
        }
    }
}

// ---------------------------------------------------------------------------
// Fallback fp32 projection (only if ws too small)
// ---------------------------------------------------------------------------
__global__ __launch_bounds__(256) void proj_kernel(
    const float* __restrict__ x, const float* __restrict__ Wm,
    const float* __restrict__ bias, bf16* __restrict__ dst, float scale,
    int transpose_v)
{
    __shared__ float As[16][64];
    __shared__ float Bs[16][64];
    const int tid  = threadIdx.x;
    const int row0 = blockIdx.y * 64;
    const int col0 = blockIdx.x * 64;
    const int ty = tid >> 4, tx = tid & 15;
    const int t4 = tid * 4;
    const int ai = t4 >> 4, aj = t4 & 15;
    const int bj = t4 >> 6, bi = t4 & 63;
    float acc[4][4] = {};
    for (int kb = 0; kb < D_MODEL; kb += 16) {
        float4 av = *(const float4*)(x  + (size_t)(row0 + ai) * D_MODEL + kb + aj);
        float4 bv = *(const float4*)(Wm + (size_t)(kb + bj)  * D_MODEL + col0 + bi);
        As[aj + 0][ai] = av.x; As[aj + 1][ai] = av.y;
        As[aj + 2][ai] = av.z; As[aj + 3][ai] = av.w;
        *(float4*)(&Bs[bj][bi]) = bv;
        __syncthreads();
#pragma unroll
        for (int k = 0; k < 16; ++k) {
            float a[4], b[4];
#pragma unroll
            for (int ii = 0; ii < 4; ++ii) a[ii] = As[k][ty * 4 + ii];
#pragma unroll
            for (int jj = 0; jj < 4; ++jj) b[jj] = Bs[k][tx * 4 + jj];
#pragma unroll
            for (int ii = 0; ii < 4; ++ii)
#pragma unroll
                for (int jj = 0; jj < 4; ++jj) acc[ii][jj] += a[ii] * b[jj];
        }
        __syncthreads();
    }
#pragma unroll
    for (int ii = 0; ii < 4; ++ii) {
        const int m = row0 + ty * 4 + ii;
        const int b = m >> 13, s = m & (S_LEN - 1);
#pragma unroll
        for (int jj = 0; jj < 4; ++jj) {
            const int n = col0 + tx * 4 + jj;
            const int h = n >> 6, d = n & 63;
            const float v = (acc[ii][jj] + bias[n]) * scale;
            if (transpose_v)
                dst[(((size_t)(b * NH + h)) * HD + d) * S_LEN + s] = __float2bfloat16(v);
            else
                dst[(((size_t)(b * NH + h)) * S_LEN + s) * HD + d] = __float2bfloat16(v);
        }
    }
}

// ---------------------------------------------------------------------------
// Flash sliding-window attention v5: v3's proven structure (K AND V double-
// buffered via global_load_lds, XOR swizzle) with 512-thread blocks:
// 8 waves x 16 queries = 128 queries/block. Staging amortizes over 8 waves,
// LDS/wave drops 10.5 KB -> 6.4 KB -> 3 blocks/CU = 24 waves/CU (75%).
// Cost: ~2 fully-masked edge tiles per wave (gated to p=0, correct).
// ---------------------------------------------------------------------------
__global__ __launch_bounds__(512) void attn_mfma5_kernel(
    const bf16* __restrict__ qw, const bf16* __restrict__ kw,
    const bf16* __restrict__ vt, float* __restrict__ out)
{
    __shared__ __align__(16) short Ksh[2][4096];     // [key][d] swizzled, 2x8KB
    __shared__ __align__(16) short Vsh[2][4096];     // [d][key] swizzled, 2x8KB
    __shared__ __align__(16) short Psh[8][16][72];   // per-wave [q][key], 18.4KB

    const int bh   = blockIdx.x;
    const int qt0  = blockIdx.y * 128;
    const int tid  = threadIdx.x;
    const int w    = tid >> 6;              // 0..7
    const int lane = tid & 63;
    const int col  = lane & 15;
    const int kg   = lane >> 4;
    const int q0   = qt0 + w * 16;
    const int q    = q0 + col;
    const size_t base = (size_t)bh * S_LEN * HD;

    const short* qg  = (const short*)qw;
    const short* kgp = (const short*)kw;
    const short* vgp = (const short*)vt;

    const int kt_lo = qt0 - WIN < 0 ? 0 : qt0 - WIN;
    const int kt_hi0 = qt0 + WIN + 64;      // covers q up to qt0+127
    const int kt_hi = kt_hi0 > S_LEN - 64 ? S_LEN - 64 : kt_hi0;
    const int NT    = ((kt_hi - kt_lo) >> 6) + 1;

    // staging: 512 chunks per array per tile, 1 per thread, XOR swizzle
    const int r0 = tid >> 3, c0 = (tid & 7) ^ (r0 & 7);
    const int ldsb = w * 64 * 8;            // wave-uniform chunk base (shorts)

    // Q B-frag: B[n=q][k=d]
    const short* qptr = qg + base + (size_t)q * HD + kg * 8;
    const short8 qB0 = *(const short8*)(qptr);
    const short8 qB1 = *(const short8*)(qptr + 32);

    const f32x4 zero4 = {0.f, 0.f, 0.f, 0.f};
    f32x4 Oacc[4] = {zero4, zero4, zero4, zero4};
    float m = -1e30f, l = 0.f;

    const int x7 = col & 7;

    // prologue: stage tile 0 into buffer 0
    gload_lds16(&Ksh[0][ldsb], kgp + base + (size_t)(kt_lo + r0) * HD + c0 * 8);
    gload_lds16(&Vsh[0][ldsb], vgp + base + (size_t)r0 * S_LEN + kt_lo + c0 * 8);

    for (int i = 0; i < NT; ++i) {
        __syncthreads();   // drains tile i's DMA (issued previous iteration)

        if (i + 1 < NT) {  // issue DMA for tile i+1 -> overlaps compute below
            const int ktn = kt_lo + 64 * (i + 1);
            const int nb = (i + 1) & 1;
            gload_lds16(&Ksh[nb][ldsb], kgp + base + (size_t)(ktn + r0) * HD + c0 * 8);
            gload_lds16(&Vsh[nb][ldsb], vgp + base + (size_t)r0 * S_LEN + ktn + c0 * 8);
        }

        const int kt = kt_lo + 64 * i;
        const short* Kb = Ksh[i & 1];
        const short* Vb = Vsh[i & 1];

        // ---- S^T = K . Q^T : A[m=key][k=d] from swizzled LDS ----
        f32x4 sc[4];
#pragma unroll
        for (int t = 0; t < 4; ++t) {
            const int key = 16 * t + col;
            const short8 kA0 = *(const short8*)(Kb + (size_t)(key * 8 + (kg ^ x7)) * 8);
            const short8 kA1 = *(const short8*)(Kb + (size_t)(key * 8 + ((kg + 4) ^ x7)) * 8);
            f32x4 a = zero4;
            a = __builtin_amdgcn_mfma_f32_16x16x32_bf16(kA0, qB0, a, 0, 0, 0);
            a = __builtin_amdgcn_mfma_f32_16x16x32_bf16(kA1, qB1, a, 0, 0, 0);
            sc[t] = a;                     // sc[t][r] = S[kt+16t+4kg+r][q]
        }

        // per-wave masking: tile fully valid iff kt >= q0+15-WIN && kt+63 <= q0+WIN
        const bool need_mask = (kt < q0 + 15 - WIN) || (kt + 63 > q0 + WIN);
        if (need_mask) {
#pragma unroll
            for (int t = 0; t < 4; ++t)
#pragma unroll
                for (int r = 0; r < 4; ++r) {
                    const int j = kt + 16 * t + kg * 4 + r;
                    if (j < q - WIN || j > q + WIN) sc[t][r] = -1e30f;
                }
        }

        // ---- per-lane online softmax + cross-kg reduce ----
        float tmax = -1e30f;
#pragma unroll
        for (int t = 0; t < 4; ++t)
#pragma unroll
            for (int r = 0; r < 4; ++r) tmax = fmaxf(tmax, sc[t][r]);
        tmax = fmaxf(tmax, __shfl_xor(tmax, 16));
        tmax = fmaxf(tmax, __shfl_xor(tmax, 32));
        const float mnew = fmaxf(m, tmax);
        const float alpha = __expf(m - mnew);
        m = mnew;

        float p[4][4];
        float rs = 0.f;
        if (need_mask) {
#pragma unroll
            for (int t = 0; t < 4; ++t)
#pragma unroll
                for (int r = 0; r < 4; ++r) {
                    const float pv = (sc[t][r] > -1e29f) ? __expf(sc[t][r] - mnew) : 0.f;
                    p[t][r] = pv; rs += pv;
                }
        } else {
#pragma unroll
            for (int t = 0; t < 4; ++t)
#pragma unroll
                for (int r = 0; r < 4; ++r) {
                    const float pv = __expf(sc[t][r] - mnew);
                    p[t][r] = pv; rs += pv;
                }
        }
        rs += __shfl_xor(rs, 16);
        rs += __shfl_xor(rs, 32);
        l = l * alpha + rs;

        // ---- P -> per-wave LDS (4x b64), read back as B-frags ----
#pragma unroll
        for (int t = 0; t < 4; ++t) {
            short4 pk;
            pk.x = f2bf(p[t][0]); pk.y = f2bf(p[t][1]);
            pk.z = f2bf(p[t][2]); pk.w = f2bf(p[t][3]);
            *(short4*)&Psh[w][col][16 * t + 4 * kg] = pk;
        }

#pragma unroll
        for (int dt = 0; dt < 4; ++dt)
#pragma unroll
            for (int r = 0; r < 4; ++r) Oacc[dt][r] *= alpha;

        const short* pp = &Psh[w][col][kg * 8];   // same-wave RAW: in-order DS
        const short8 pB0 = *(const short8*)(pp);
        const short8 pB1 = *(const short8*)(pp + 32);

        // ---- O^T += V^T . P^T : A[m=d][k=key] from swizzled LDS ----
#pragma unroll
        for (int dt = 0; dt < 4; ++dt) {
            const int d = dt * 16 + col;
            const short8 vA0 = *(const short8*)(Vb + (size_t)(d * 8 + (kg ^ x7)) * 8);
            const short8 vA1 = *(const short8*)(Vb + (size_t)(d * 8 + ((kg + 4) ^ x7)) * 8);
            Oacc[dt] = __builtin_amdgcn_mfma_f32_16x16x32_bf16(vA0, pB0, Oacc[dt], 0, 0, 0);
            Oacc[dt] = __builtin_amdgcn_mfma_f32_16x16x32_bf16(vA1, pB1, Oacc[dt], 0, 0, 0);
        }
    }

    // ---- epilogue: coalesced float4 stores ----
    const float inv = 1.0f / l;
    const int b = bh >> 3, h = bh & 7;
    float* op = out + ((size_t)(b * S_LEN + q)) * D_MODEL + h * HD + kg * 4;
#pragma unroll
    for (int dt = 0; dt < 4; ++dt) {
        float4 o;
        o.x = Oacc[dt][0] * inv; o.y = Oacc[dt][1] * inv;
        o.z = Oacc[dt][2] * inv; o.w = Oacc[dt][3] * inv;
        *(float4*)(op + dt * 16) = o;
    }
}

// ---------------------------------------------------------------------------
extern "C" void kernel_launch(void* const* d_in, const int* in_sizes, int n_in,
                              void* d_out, int out_size, void* d_ws, size_t ws_size,
                              hipStream_t stream)
{
    const float* x  = (const float*)d_in[0];
    const float* Wq = (const float*)d_in[1];
    const float* bq = (const float*)d_in[2];
    const float* Wk = (const float*)d_in[3];
    const float* bk = (const float*)d_in[4];
    const float* Wv = (const float*)d_in[5];
    const float* bv = (const float*)d_in[6];
    float* out = (float*)d_out;

    const size_t n_elem = (size_t)NB * NH * S_LEN * HD;
    bf16* qw = (bf16*)d_ws;
    bf16* kw = qw + n_elem;
    bf16* vw = kw + n_elem;        // v TRANSPOSED: [bh][d][s]
    short* xb = (short*)(vw + n_elem);
    short* wT = xb + (size_t)NB * S_LEN * D_MODEL;

    const size_t need = (3 * n_elem + (size_t)NB * S_LEN * D_MODEL +
                         3 * (size_t)D_MODEL * D_MODEL) * sizeof(short);

    if (ws_size >= need) {
        convert_x_kernel<<<2048, 256, 0, stream>>>(x, xb);
        dim3 wgrid(D_MODEL / 32, D_MODEL / 32, 3);
        convert_wT_kernel<<<wgrid, 256, 0, stream>>>(Wq, Wk, Wv, wT);
        dim3 ggrid(12, (NB * S_LEN) / 128);
        proj_mfma_kernel<<<ggrid, 256, 0, stream>>>(xb, wT, bq, bk, bv, qw);
    } else {
        dim3 pgrid(D_MODEL / 64, (NB * S_LEN) / 64);
        proj_kernel<<<pgrid, 256, 0, stream>>>(x, Wq, bq, qw, 0.125f, 0);
        proj_kernel<<<pgrid, 256, 0, stream>>>(x, Wk, bk, kw, 1.0f, 0);
        proj_kernel<<<pgrid, 256, 0, stream>>>(x, Wv, bv, vw, 1.0f, 1);
    }

    dim3 agrid(NB * NH, S_LEN / 128);
    attn_mfma5_kernel<<<agrid, 512, 0, stream>>>(qw, kw, vw, out);
}